// Round 1
// baseline (111.393 us; speedup 1.0000x reference)
//
#include <hip/hip_runtime.h>

constexpr int N_NODES = 50000;
constexpr int KNB = 12;       // neighbors per node
constexpr int F = 128;        // F_IN == F_OUT
constexpr float ALPHA = 0.2f; // LeakyReLU slope
constexpr int MTILE = 32;     // nodes per block in GEMM kernel

// Fused: act_self = x@W_self (+bias) -> out ; h = x@W_neighbor -> ws
//        s_in = h@a[:128], s_out = h@a[128:] -> ws
// Block: 256 threads. Thread t: tc = t&31 -> 4 cols (tc*4..+3), tr = t>>5 -> 4 nodes (tr*4..+3).
// LDS: x tile [32][128] (16KB) + two W k-tiles [32][128] (16KB each) = 48KB.
__global__ __launch_bounds__(256, 2) void gat_gemm(
    const float* __restrict__ x,
    const float* __restrict__ Wself,
    const float* __restrict__ Wnb,
    const float* __restrict__ a,
    const float* __restrict__ bias,
    float* __restrict__ out,
    float* __restrict__ h,
    float* __restrict__ s_in,
    float* __restrict__ s_out)
{
    __shared__ float xs[MTILE][F];
    __shared__ float wst[32][F];
    __shared__ float wnt[32][F];

    const int t = threadIdx.x;
    const int tc = t & 31;
    const int tr = t >> 5;
    const int node_base = blockIdx.x * MTILE;

    // Load x tile (1024 float4s across 256 threads), clamp OOB rows to last node.
#pragma unroll
    for (int j = 0; j < 4; ++j) {
        const int idx4 = t + j * 256;   // float4 index within tile
        const int r = idx4 >> 5;        // 32 float4 per row
        const int c4 = idx4 & 31;
        int gr = node_base + r;
        if (gr >= N_NODES) gr = N_NODES - 1;
        reinterpret_cast<float4*>(&xs[r][0])[c4] =
            reinterpret_cast<const float4*>(x + (size_t)gr * F)[c4];
    }

    float4 accS[4], accN[4];
#pragma unroll
    for (int i = 0; i < 4; ++i) {
        accS[i] = float4{0.f, 0.f, 0.f, 0.f};
        accN[i] = float4{0.f, 0.f, 0.f, 0.f};
    }

    const int r0 = tr * 4;
    for (int kk = 0; kk < F; kk += 32) {
        __syncthreads();
        // Stage W k-tiles (32x128 each)
#pragma unroll
        for (int j = 0; j < 4; ++j) {
            const int idx4 = t + j * 256;
            const int r = idx4 >> 5;
            const int c4 = idx4 & 31;
            reinterpret_cast<float4*>(&wst[r][0])[c4] =
                reinterpret_cast<const float4*>(Wself + (size_t)(kk + r) * F)[c4];
            reinterpret_cast<float4*>(&wnt[r][0])[c4] =
                reinterpret_cast<const float4*>(Wnb + (size_t)(kk + r) * F)[c4];
        }
        __syncthreads();
#pragma unroll
        for (int k = 0; k < 32; ++k) {
            const float4 ws4 = reinterpret_cast<const float4*>(&wst[k][0])[tc];
            const float4 wn4 = reinterpret_cast<const float4*>(&wnt[k][0])[tc];
#pragma unroll
            for (int i = 0; i < 4; ++i) {
                const float xv = xs[r0 + i][kk + k];
                accS[i].x = fmaf(xv, ws4.x, accS[i].x);
                accS[i].y = fmaf(xv, ws4.y, accS[i].y);
                accS[i].z = fmaf(xv, ws4.z, accS[i].z);
                accS[i].w = fmaf(xv, ws4.w, accS[i].w);
                accN[i].x = fmaf(xv, wn4.x, accN[i].x);
                accN[i].y = fmaf(xv, wn4.y, accN[i].y);
                accN[i].z = fmaf(xv, wn4.z, accN[i].z);
                accN[i].w = fmaf(xv, wn4.w, accN[i].w);
            }
        }
    }

    const float4 b4  = reinterpret_cast<const float4*>(bias)[tc];
    const float4 alo = reinterpret_cast<const float4*>(a)[tc];
    const float4 ahi = reinterpret_cast<const float4*>(a + F)[tc];

#pragma unroll
    for (int i = 0; i < 4; ++i) {
        const int node = node_base + r0 + i;
        // partial dots for s_in/s_out over this thread's 4 columns
        float pin  = accN[i].x * alo.x + accN[i].y * alo.y + accN[i].z * alo.z + accN[i].w * alo.w;
        float pout = accN[i].x * ahi.x + accN[i].y * ahi.y + accN[i].z * ahi.z + accN[i].w * ahi.w;
        // reduce across the 32 tc-lanes (xor<=16 stays in the 32-lane half-wave)
#pragma unroll
        for (int m = 16; m >= 1; m >>= 1) {
            pin  += __shfl_xor(pin,  m);
            pout += __shfl_xor(pout, m);
        }
        if (node < N_NODES) {
            float4 o;
            o.x = accS[i].x + b4.x; o.y = accS[i].y + b4.y;
            o.z = accS[i].z + b4.z; o.w = accS[i].w + b4.w;
            reinterpret_cast<float4*>(out + (size_t)node * F)[tc] = o;
            reinterpret_cast<float4*>(h   + (size_t)node * F)[tc] = accN[i];
            if (tc == 0) { s_in[node] = pin; s_out[node] = pout; }
        }
    }
}

// Per node: e_j = lrelu(s_in[node] + s_out[col_j]); softmax over K=12; fold adj_vals;
// out[node,:] += sum_j att_j * h[col_j,:]
// Edges are sorted by row with exactly K per node, so edge e belongs to node e/K.
__global__ __launch_bounds__(128) void gat_attn(
    const float* __restrict__ h,
    const float* __restrict__ s_in,
    const float* __restrict__ s_out,
    const int* __restrict__ colidx,
    const float* __restrict__ adj,
    float* __restrict__ out)
{
    const int node = blockIdx.x;
    const int t = threadIdx.x;
    __shared__ float att[KNB];
    __shared__ int cols[KNB];

    if (t < KNB) {
        const int e = node * KNB + t;
        const int c = colidx[e];
        cols[t] = c;
        float ev = s_in[node] + s_out[c];
        ev = ev > 0.f ? ev : ALPHA * ev;
        att[t] = ev;
    }
    __syncthreads();
    if (t == 0) {
        float m = att[0];
#pragma unroll
        for (int j = 1; j < KNB; ++j) m = fmaxf(m, att[j]);
        float p[KNB];
        float s = 0.f;
#pragma unroll
        for (int j = 0; j < KNB; ++j) { p[j] = __expf(att[j] - m); s += p[j]; }
        const float inv = 1.f / s;
#pragma unroll
        for (int j = 0; j < KNB; ++j) att[j] = p[j] * inv * adj[node * KNB + j];
    }
    __syncthreads();

    float acc = 0.f;
#pragma unroll
    for (int j = 0; j < KNB; ++j) {
        acc = fmaf(att[j], h[(size_t)cols[j] * F + t], acc);
    }
    const size_t o = (size_t)node * F + t;
    out[o] += acc;   // add neighbor aggregation onto act_self + bias
}

extern "C" void kernel_launch(void* const* d_in, const int* in_sizes, int n_in,
                              void* d_out, int out_size, void* d_ws, size_t ws_size,
                              hipStream_t stream) {
    const float* x     = (const float*)d_in[0];
    const float* adj   = (const float*)d_in[1];
    // d_in[2] = row: implicit (edges sorted, exactly K per node)
    const int*   col   = (const int*)d_in[3];
    const float* Wself = (const float*)d_in[4];
    const float* Wnb   = (const float*)d_in[5];
    const float* a     = (const float*)d_in[6];
    const float* bias  = (const float*)d_in[7];
    float* out = (float*)d_out;

    float* ws    = (float*)d_ws;
    float* h     = ws;                               // N*F floats (25.6 MB)
    float* s_in  = ws + (size_t)N_NODES * F;         // N floats
    float* s_out = s_in + N_NODES;                   // N floats

    const int g1 = (N_NODES + MTILE - 1) / MTILE;
    gat_gemm<<<g1, 256, 0, stream>>>(x, Wself, Wnb, a, bias, out, h, s_in, s_out);
    gat_attn<<<N_NODES, 128, 0, stream>>>(h, s_in, s_out, col, adj, out);
}

// Round 2
// 55.675 us; speedup vs baseline: 2.0008x; 2.0008x over previous
//
#include <hip/hip_runtime.h>

constexpr int N_NODES = 50000;
constexpr int KNB = 12;       // neighbors per node
constexpr int F = 128;        // F_IN == F_OUT
constexpr float ALPHA = 0.2f; // LeakyReLU slope
constexpr int BM = 64;        // nodes per GEMM block

typedef __bf16 bf16x8 __attribute__((ext_vector_type(8)));
typedef float  f32x4  __attribute__((ext_vector_type(4)));

__device__ __forceinline__ unsigned bfr(float f) {
    // round-to-nearest-even f32 -> bf16 bits
    unsigned u = __float_as_uint(f);
    return (u + 0x7fffu + ((u >> 16) & 1u)) >> 16;
}
__device__ __forceinline__ unsigned pack2(float lo, float hi) {
    return bfr(lo) | (bfr(hi) << 16);
}
__device__ __forceinline__ float bf2f(unsigned bits16) {
    return __uint_as_float(bits16 << 16);
}

// ---------------- Kernel 0: W transpose + bf16 ----------------
// Wt[n][k] bf16, n in [0,256): n<128 -> Wself[:,n], else Wnb[:,n-128].
// Stored as u32 pairs: Wt_u32[n*64 + kp] = (bf(W[2kp+1][n])<<16) | bf(W[2kp][n])
__global__ __launch_bounds__(256) void gat_prep(const float* __restrict__ Wself,
                                                const float* __restrict__ Wnb,
                                                unsigned* __restrict__ Wt) {
    const int gid = blockIdx.x * 256 + threadIdx.x;  // 16384 total
    const int n  = gid >> 6;
    const int kp = gid & 63;
    const float* src = (n < F) ? (Wself + n) : (Wnb + (n - F));
    const float f0 = src[(size_t)(kp * 2)     * F];
    const float f1 = src[(size_t)(kp * 2 + 1) * F];
    Wt[n * 64 + kp] = pack2(f0, f1);
}

// ---------------- Kernel 1: fused dual GEMM via MFMA ----------------
// out[node] = x@Wself + bias (fp32) ; hb[node] = bf16(x@Wnb) ;
// s_in = h@a[:128], s_out = h@a[128:]  (from fp32 accumulators)
// Block: 256 thr = 4 waves; tile 64 rows x 256 cols; K=128 in 4 steps of 32.
// LDS 80KB: X tile 16KB + W 64KB, both 16B-fragment layout with XOR swizzle
// (byte ^= (row&7)<<4) so ds_read_b128 fragment reads are bank-balanced.
__global__ __launch_bounds__(256, 2) void gat_gemm(
    const float* __restrict__ x,
    const unsigned* __restrict__ Wt,   // [256][64] u32 (bf16 pairs)
    const float* __restrict__ a,
    const float* __restrict__ bias,
    float* __restrict__ out,
    unsigned short* __restrict__ hb,   // bf16 h
    float* __restrict__ s_in,
    float* __restrict__ s_out)
{
    __shared__ uint4 ldsX[BM * 16];    // 64 rows x 16 frags(8 bf16)
    __shared__ uint4 ldsW[256 * 16];   // 256 n   x 16 frags

    const int t = threadIdx.x;
    const int base = blockIdx.x * BM;

    // ---- stage X tile (fp32 -> bf16), coalesced 32B/lane ----
#pragma unroll
    for (int i = 0; i < 4; ++i) {
        const int idx = t + i * 256;       // 0..1023
        const int row = idx >> 4;
        const int k16 = idx & 15;
        int gr = base + row; if (gr >= N_NODES) gr = N_NODES - 1;
        const float4* xp = reinterpret_cast<const float4*>(x + (size_t)gr * F + k16 * 8);
        const float4 f0 = xp[0];
        const float4 f1 = xp[1];
        uint4 v;
        v.x = pack2(f0.x, f0.y); v.y = pack2(f0.z, f0.w);
        v.z = pack2(f1.x, f1.y); v.w = pack2(f1.z, f1.w);
        ldsX[row * 16 + (k16 ^ (row & 7))] = v;
    }
    // ---- stage W (already bf16, already transposed) ----
    const uint4* Wt4 = reinterpret_cast<const uint4*>(Wt);
#pragma unroll
    for (int i = 0; i < 16; ++i) {
        const int idx = t + i * 256;       // 0..4095 ; idx = n*16 + k16
        const int n   = idx >> 4;
        const int k16 = idx & 15;
        ldsW[n * 16 + (k16 ^ (n & 7))] = Wt4[idx];
    }
    __syncthreads();

    const int wid = t >> 6;
    const int lane = t & 63;
    const int lq = lane >> 4;   // quad 0..3
    const int lr = lane & 15;
    const int wm = wid >> 1;    // 0..1: rows wm*32..+32
    const int wn = wid & 1;     // 0: self-half (out), 1: neighbor-half (h)

    const bf16x8* fx = reinterpret_cast<const bf16x8*>(ldsX);
    const bf16x8* fw = reinterpret_cast<const bf16x8*>(ldsW);

    f32x4 acc[2][8];
#pragma unroll
    for (int mt = 0; mt < 2; ++mt)
#pragma unroll
        for (int nt = 0; nt < 8; ++nt)
            acc[mt][nt] = f32x4{0.f, 0.f, 0.f, 0.f};

#pragma unroll
    for (int s = 0; s < 4; ++s) {
        bf16x8 af[2];
#pragma unroll
        for (int mt = 0; mt < 2; ++mt) {
            const int row = wm * 32 + mt * 16 + lr;
            af[mt] = fx[row * 16 + ((s * 4 + lq) ^ (row & 7))];
        }
        bf16x8 bw[8];
#pragma unroll
        for (int nt = 0; nt < 8; ++nt) {
            const int n = wn * 128 + nt * 16 + lr;
            bw[nt] = fw[n * 16 + ((s * 4 + lq) ^ (n & 7))];
        }
#pragma unroll
        for (int mt = 0; mt < 2; ++mt)
#pragma unroll
            for (int nt = 0; nt < 8; ++nt)
                acc[mt][nt] = __builtin_amdgcn_mfma_f32_16x16x32_bf16(af[mt], bw[nt], acc[mt][nt], 0, 0, 0);
    }

    // Epilogue. D mapping (m89): D[(lq*4 + r)][lr] per 16x16 tile.
    if (wn == 0) {
        float bv[8];
#pragma unroll
        for (int nt = 0; nt < 8; ++nt) bv[nt] = bias[nt * 16 + lr];
#pragma unroll
        for (int mt = 0; mt < 2; ++mt)
#pragma unroll
            for (int r = 0; r < 4; ++r) {
                const int row = base + wm * 32 + mt * 16 + lq * 4 + r;
                if (row < N_NODES) {
#pragma unroll
                    for (int nt = 0; nt < 8; ++nt)
                        out[(size_t)row * F + nt * 16 + lr] = acc[mt][nt][r] + bv[nt];
                }
            }
    } else {
        float alo[8], ahi[8];
#pragma unroll
        for (int nt = 0; nt < 8; ++nt) {
            alo[nt] = a[nt * 16 + lr];
            ahi[nt] = a[F + nt * 16 + lr];
        }
#pragma unroll
        for (int mt = 0; mt < 2; ++mt)
#pragma unroll
            for (int r = 0; r < 4; ++r) {
                const int row = base + wm * 32 + mt * 16 + lq * 4 + r;  // uniform across lr-group
                float pin = 0.f, pout = 0.f;
#pragma unroll
                for (int nt = 0; nt < 8; ++nt) {
                    const float v = acc[mt][nt][r];
                    pin  = fmaf(v, alo[nt], pin);
                    pout = fmaf(v, ahi[nt], pout);
                }
                // reduce over the 16 lr-lanes (masks 1..8 stay inside the group)
#pragma unroll
                for (int msk = 8; msk >= 1; msk >>= 1) {
                    pin  += __shfl_xor(pin,  msk);
                    pout += __shfl_xor(pout, msk);
                }
                if (row < N_NODES) {
#pragma unroll
                    for (int nt = 0; nt < 8; ++nt)
                        hb[(size_t)row * F + nt * 16 + lr] = (unsigned short)bfr(acc[mt][nt][r]);
                    if (lr == 0) { s_in[row] = pin; s_out[row] = pout; }
                }
            }
    }
}

// ---------------- Kernel 2: attention + aggregation ----------------
// One 64-lane wave per node. Lanes 0..11 own the K=12 edges; softmax via
// shfl reductions in the low 16-lane group; each lane aggregates 2 features.
__global__ __launch_bounds__(256) void gat_attn(
    const unsigned* __restrict__ hb32,   // h bf16 as u32 pairs: [N][64]
    const float* __restrict__ s_in,
    const float* __restrict__ s_out,
    const int* __restrict__ colidx,
    const float* __restrict__ adj,
    float* __restrict__ out)
{
    const int wid = threadIdx.x >> 6;
    const int lane = threadIdx.x & 63;
    const int node = blockIdx.x * 4 + wid;   // grid*4 == N exactly

    float e = -1e30f;
    int c = 0;
    float av = 0.f;
    if (lane < KNB) {
        c  = colidx[node * KNB + lane];
        av = adj[node * KNB + lane];
        const float ev = s_in[node] + s_out[c];
        e = ev > 0.f ? ev : ALPHA * ev;
    }
    float m = e;
#pragma unroll
    for (int msk = 8; msk >= 1; msk >>= 1) m = fmaxf(m, __shfl_xor(m, msk));
    const float p = (lane < KNB) ? __expf(e - m) : 0.f;
    float ssum = p;
#pragma unroll
    for (int msk = 8; msk >= 1; msk >>= 1) ssum += __shfl_xor(ssum, msk);
    const float att = p / ssum * av;   // lanes >= 16 may produce NaN; never read

    float accx = 0.f, accy = 0.f;
#pragma unroll
    for (int j = 0; j < KNB; ++j) {
        const float aj = __shfl(att, j);
        const int   cj = __shfl(c, j);
        const unsigned u = hb32[(size_t)cj * 64 + lane];   // 256B/row, coalesced
        accx = fmaf(aj, bf2f(u & 0xffffu), accx);
        accy = fmaf(aj, bf2f(u >> 16), accy);
    }
    float2* op = reinterpret_cast<float2*>(out + (size_t)node * F) + lane;
    float2 o = *op;
    o.x += accx; o.y += accy;
    *op = o;
}

extern "C" void kernel_launch(void* const* d_in, const int* in_sizes, int n_in,
                              void* d_out, int out_size, void* d_ws, size_t ws_size,
                              hipStream_t stream) {
    const float* x     = (const float*)d_in[0];
    const float* adj   = (const float*)d_in[1];
    // d_in[2] = row: implicit (edges sorted, exactly K per node)
    const int*   col   = (const int*)d_in[3];
    const float* Wself = (const float*)d_in[4];
    const float* Wnb   = (const float*)d_in[5];
    const float* a     = (const float*)d_in[6];
    const float* bias  = (const float*)d_in[7];
    float* out = (float*)d_out;

    char* ws = (char*)d_ws;
    unsigned short* hb = (unsigned short*)ws;            // 50000*128*2 = 12,800,000 B
    float* s_in  = (float*)(ws + 12800000);              // 200,000 B
    float* s_out = (float*)(ws + 13000000);              // 200,000 B
    unsigned* Wt = (unsigned*)(ws + 13200000);           // 65,536 B

    gat_prep<<<64, 256, 0, stream>>>(Wself, Wnb, Wt);
    gat_gemm<<<(N_NODES + BM - 1) / BM, 256, 0, stream>>>(x, Wt, a, bias, out, hb, s_in, s_out);
    gat_attn<<<N_NODES / 4, 256, 0, stream>>>((const unsigned*)hb, s_in, s_out, col, adj, out);
}